// Round 2
// baseline (1018.470 us; speedup 1.0000x reference)
//
#include <hip/hip_runtime.h>

// ---------------- types ----------------
typedef __bf16 bf16;
typedef __bf16 bf16x4 __attribute__((ext_vector_type(4)));
typedef __bf16 bf16x8 __attribute__((ext_vector_type(8)));
typedef float  f32x4  __attribute__((ext_vector_type(4)));

// Problem constants: b=64, a=8 -> 512 slices total, processed in 8 groups of SG=64.
// f=F=256 (DIM), t=T=256, 3*hidden=1536, heads=4, c=128
#define TT    256
#define FF    256
#define SG    64          // slices per group
#define NGRP  8

static __device__ inline f32x4 mfma16(bf16x8 a, bf16x8 b, f32x4 c) {
    return __builtin_amdgcn_mfma_f32_16x16x32_bf16(a, b, c, 0, 0, 0);
}

// Stage a [128 x 32] bf16 tile (row-major, leading dim ld) into LDS with row stride 40.
static __device__ inline void stage128(const bf16* __restrict__ g, int ld, bf16* __restrict__ l) {
    int tid = threadIdx.x;
#pragma unroll
    for (int it = 0; it < 2; it++) {
        int ch = it * 256 + tid;        // 512 chunks of 8 elts
        int r = ch >> 2, cc = ch & 3;
        *(bf16x8*)(l + r * 40 + cc * 8) = *(const bf16x8*)(g + (size_t)r * ld + cc * 8);
    }
}
// Stage a [256 x 32] bf16 tile into LDS with row stride 40.
static __device__ inline void stage256(const bf16* __restrict__ g, int ld, bf16* __restrict__ l) {
    int tid = threadIdx.x;
#pragma unroll
    for (int it = 0; it < 4; it++) {
        int ch = it * 256 + tid;        // 1024 chunks
        int r = ch >> 2, cc = ch & 3;
        *(bf16x8*)(l + r * 40 + cc * 8) = *(const bf16x8*)(g + (size_t)r * ld + cc * 8);
    }
}
// Fragment load: lane holds row (row0 + lane&15), k = (lane>>4)*8 + j  (j=0..7)
static __device__ inline bf16x8 fragld(const bf16* __restrict__ l, int row0, int stride) {
    int lane = threadIdx.x & 63;
    return *(const bf16x8*)(l + (row0 + (lane & 15)) * stride + (lane >> 4) * 8);
}

// ---------------- small prep kernels ----------------
// fp32 -> bf16, 4 elts/thread, grid = n/1024 exactly
__global__ __launch_bounds__(256) void k_cvt(const float4* __restrict__ src, bf16* __restrict__ dst) {
    int i = blockIdx.x * 256 + threadIdx.x;
    float4 v = src[i];
    bf16x4 o;
    o[0] = (__bf16)v.x; o[1] = (__bf16)v.y; o[2] = (__bf16)v.z; o[3] = (__bf16)v.w;
    *(bf16x4*)(dst + (size_t)i * 4) = o;
}

// mish(time) fp32 -> bf16, layout [512][256]; grid 128 (4 elts/thread)
__global__ __launch_bounds__(256) void k_mish(const float4* __restrict__ src, bf16* __restrict__ dst) {
    int i = blockIdx.x * 256 + threadIdx.x;
    float4 v = src[i];
    float in[4] = {v.x, v.y, v.z, v.w};
    bf16x4 o;
#pragma unroll
    for (int j = 0; j < 4; j++) {
        float sp = log1pf(__expf(in[j]));
        o[j] = (__bf16)(in[j] * tanhf(sp));
    }
    *(bf16x4*)(dst + (size_t)i * 4) = o;
}

// x [s][f][t] fp32 -> xT [s][t][f] bf16 (64x64 LDS tiles); grid = SG*16, s is group-local
__global__ __launch_bounds__(256) void k_xpose(const float* __restrict__ x, bf16* __restrict__ xT) {
    __shared__ float tile[64][65];
    int bid = blockIdx.x;
    int s  = bid >> 4;                 // 0..63 group-local
    int f0 = ((bid >> 2) & 3) * 64;
    int t0 = (bid & 3) * 64;
    int tid = threadIdx.x;
    int rr = tid >> 4;           // 0..15
    int cc = (tid & 15) * 4;     // 0..60
    const float* xp = x + ((size_t)(s * FF + f0)) * TT + t0;
#pragma unroll
    for (int i = 0; i < 4; i++) {
        int r = i * 16 + rr;
        float4 v = *(const float4*)(xp + (size_t)r * TT + cc);
        tile[r][cc] = v.x; tile[r][cc + 1] = v.y; tile[r][cc + 2] = v.z; tile[r][cc + 3] = v.w;
    }
    __syncthreads();
    bf16* op = xT + ((size_t)(s * TT + t0)) * FF + f0;
#pragma unroll
    for (int i = 0; i < 4; i++) {
        int tr = i * 16 + rr;
        bf16x4 o;
        o[0] = (__bf16)tile[cc][tr];     o[1] = (__bf16)tile[cc + 1][tr];
        o[2] = (__bf16)tile[cc + 2][tr]; o[3] = (__bf16)tile[cc + 3][tr];
        *(bf16x4*)(op + (size_t)tr * FF + cc) = o;
    }
}

// ---------------- temb GEMM: tembT[o][sg] = w_time[o][:] . mish[sg][:] + b_time[o] ----------------
// grid (12, 4), Mtile=128(o), Ntile=128(sg over all 512), K=256. Runs once (global).
__global__ __launch_bounds__(256) void k_temb(const bf16* __restrict__ wt, const bf16* __restrict__ mish,
                                              const float* __restrict__ bt, float* __restrict__ tembT) {
    __shared__ bf16 lA[128 * 40];
    __shared__ bf16 lB[128 * 40];
    int o0 = blockIdx.x * 128, s0 = blockIdx.y * 128;
    int tid = threadIdx.x, wv = tid >> 6, lane = tid & 63, qd = lane >> 4, c = lane & 15;
    f32x4 acc[2][8] = {};
    for (int k0 = 0; k0 < 256; k0 += 32) {
        __syncthreads();
        stage128(wt + (size_t)o0 * 256 + k0, 256, lA);
        stage128(mish + (size_t)s0 * 256 + k0, 256, lB);
        __syncthreads();
        bf16x8 a0 = fragld(lA, wv * 32, 40), a1 = fragld(lA, wv * 32 + 16, 40);
#pragma unroll
        for (int nt = 0; nt < 8; nt++) {
            bf16x8 b = fragld(lB, nt * 16, 40);
            acc[0][nt] = mfma16(a0, b, acc[0][nt]);
            acc[1][nt] = mfma16(a1, b, acc[1][nt]);
        }
    }
#pragma unroll
    for (int mt = 0; mt < 2; mt++)
#pragma unroll
        for (int nt = 0; nt < 8; nt++)
#pragma unroll
            for (int r = 0; r < 4; r++) {
                int o = o0 + wv * 32 + mt * 16 + qd * 4 + r;
                int s = s0 + nt * 16 + c;
                tembT[(size_t)o * 512 + s] = acc[mt][nt][r] + bt[o];
            }
}

// ---------------- qkv GEMM: per (mc, s_local): D[128 o][256 t] = W[o][f] xT[t][f] + temb ----------------
// grid (12, SG). mc: sec = mc>>2 (0=q,1=k,2=v), h = mc&3.
// q -> qT[s][h][t][d] ; k,v -> [s][h][d][t]   (s group-local). tembT pre-offset by group.
__global__ __launch_bounds__(256) void k_qkv(const bf16* __restrict__ wq, const bf16* __restrict__ xT,
                                             const float* __restrict__ tembT,
                                             bf16* __restrict__ qt, bf16* __restrict__ kk, bf16* __restrict__ vv) {
    __shared__ bf16 lA[128 * 40];
    __shared__ bf16 lB[256 * 40];
    int mc = blockIdx.x, s = blockIdx.y;
    int o0 = mc * 128;
    int tid = threadIdx.x, wv = tid >> 6, lane = tid & 63, qd = lane >> 4, c = lane & 15;
    const bf16* xs = xT + (size_t)s * (TT * FF);
    f32x4 acc[2][16] = {};
    for (int k0 = 0; k0 < 256; k0 += 32) {
        __syncthreads();
        stage128(wq + (size_t)o0 * 256 + k0, 256, lA);
        stage256(xs + k0, 256, lB);
        __syncthreads();
        bf16x8 a0 = fragld(lA, wv * 32, 40), a1 = fragld(lA, wv * 32 + 16, 40);
#pragma unroll
        for (int nt = 0; nt < 16; nt++) {
            bf16x8 b = fragld(lB, nt * 16, 40);
            acc[0][nt] = mfma16(a0, b, acc[0][nt]);
            acc[1][nt] = mfma16(a1, b, acc[1][nt]);
        }
    }
    int sec = mc >> 2, h = mc & 3;
    float tb[2][4];
#pragma unroll
    for (int mt = 0; mt < 2; mt++)
#pragma unroll
        for (int r = 0; r < 4; r++)
            tb[mt][r] = tembT[(size_t)(o0 + wv * 32 + mt * 16 + qd * 4 + r) * 512 + s];
    if (sec == 0) {
#pragma unroll
        for (int mt = 0; mt < 2; mt++)
#pragma unroll
            for (int nt = 0; nt < 16; nt++) {
                int t = nt * 16 + c, dl = wv * 32 + mt * 16 + qd * 4;
                bf16x4 o;
#pragma unroll
                for (int r = 0; r < 4; r++) o[r] = (__bf16)(acc[mt][nt][r] + tb[mt][r]);
                *(bf16x4*)(qt + (((size_t)s * 4 + h) * 256 + t) * 128 + dl) = o;
            }
    } else {
        bf16* dst0 = (sec == 1 ? kk : vv);
#pragma unroll
        for (int mt = 0; mt < 2; mt++)
#pragma unroll
            for (int nt = 0; nt < 16; nt++) {
                int t = nt * 16 + c, dl = wv * 32 + mt * 16 + qd * 4;
                bf16* d = dst0 + (((size_t)s * 4 + h) * 128 + dl) * 256 + t;
#pragma unroll
                for (int r = 0; r < 4; r++) d[(size_t)r * 256] = (__bf16)(acc[mt][nt][r] + tb[mt][r]);
            }
    }
}

// ---------------- fused attention per (s_local, h): softmax(k) stats + ct = v expk^T + out = ct q ----------------
// grid SG*4. Writes midT[s][t][h*128+e].
__global__ __launch_bounds__(256) void k_attn(const bf16* __restrict__ kk, const bf16* __restrict__ vv,
                                              const bf16* __restrict__ qt, bf16* __restrict__ midT) {
    __shared__ __align__(16) char smem[56320];
    float* mx = (float*)smem;            // [128]
    float* rs = mx + 128;                // [128]
    bf16* lA  = (bf16*)(smem + 1024);            // v tile  [128][40]
    bf16* lB  = (bf16*)(smem + 1024 + 10240);    // k tile  [128][40]
    bf16* lQ  = (bf16*)(smem + 1024);            // q tile  [256][40] (aliases lA+lB)
    bf16* lct = (bf16*)(smem + 1024 + 20480);    // ct [128][136]
    int bid = blockIdx.x;
    int s = bid >> 2, h = bid & 3;
    size_t base = ((size_t)s * 4 + h) * 32768;   // 128*256
    const bf16* kb = kk + base;
    const bf16* vb = vv + base;
    int tid = threadIdx.x, wv = tid >> 6, lane = tid & 63, qd = lane >> 4, c = lane & 15;

    // phase 1: softmax stats per k-row (online max/sum), 2 threads per row
    {
        int d = tid >> 1, half = tid & 1;
        const bf16* p = kb + (size_t)d * 256 + half * 128;
        float m = -3e38f, l = 0.f;
#pragma unroll
        for (int ci = 0; ci < 16; ci++) {
            bf16x8 v8 = *(const bf16x8*)(p + ci * 8);
            float xv[8]; float cm = -3e38f;
#pragma unroll
            for (int j = 0; j < 8; j++) { xv[j] = (float)v8[j]; cm = fmaxf(cm, xv[j]); }
            if (cm > m) { l *= __expf(m - cm); m = cm; }
#pragma unroll
            for (int j = 0; j < 8; j++) l += __expf(xv[j] - m);
        }
        float mo = __shfl_xor(m, 1);
        float lo = __shfl_xor(l, 1);
        float M = fmaxf(m, mo);
        float L = l * __expf(m - M) + lo * __expf(mo - M);
        if (half == 0) { mx[d] = M; rs[d] = 1.0f / L; }
    }
    __syncthreads();

    // phase 2: ct[e][d] = sum_t v[e,t] * exp(k[d,t]-mx[d])   (A=v, B=exp(k))
    f32x4 cacc[2][8] = {};
    for (int k0 = 0; k0 < 256; k0 += 32) {
        __syncthreads();
        stage128(vb + k0, 256, lA);
        stage128(kb + k0, 256, lB);
        __syncthreads();
        bf16x8 a0 = fragld(lA, wv * 32, 40), a1 = fragld(lA, wv * 32 + 16, 40);
#pragma unroll
        for (int nt = 0; nt < 8; nt++) {
            bf16x8 kf = fragld(lB, nt * 16, 40);
            float md = mx[nt * 16 + c];
            bf16x8 b;
#pragma unroll
            for (int j = 0; j < 8; j++) b[j] = (__bf16)__expf((float)kf[j] - md);
            cacc[0][nt] = mfma16(a0, b, cacc[0][nt]);
            cacc[1][nt] = mfma16(a1, b, cacc[1][nt]);
        }
    }
    __syncthreads();
    // phase 3a: ct -> LDS [e][d] (stride 136), scaled by 1/sum
#pragma unroll
    for (int mt = 0; mt < 2; mt++)
#pragma unroll
        for (int nt = 0; nt < 8; nt++) {
            int d = nt * 16 + c;
            float rv = rs[d];
#pragma unroll
            for (int r = 0; r < 4; r++) {
                int e = wv * 32 + mt * 16 + qd * 4 + r;
                lct[e * 136 + d] = (__bf16)(cacc[mt][nt][r] * rv);
            }
        }
    __syncthreads();
    // phase 3b: out[e][t] = sum_d ct[e][d] q[d][t]  (B from qT[t][d])
    const bf16* qb = qt + base;
    f32x4 oacc[2][16] = {};
    for (int d0 = 0; d0 < 128; d0 += 32) {
        __syncthreads();
        stage256(qb + d0, 128, lQ);
        __syncthreads();
        bf16x8 a0 = fragld(lct + d0, wv * 32, 136), a1 = fragld(lct + d0, wv * 32 + 16, 136);
#pragma unroll
        for (int nt = 0; nt < 16; nt++) {
            bf16x8 qf = fragld(lQ, nt * 16, 40);
            oacc[0][nt] = mfma16(a0, qf, oacc[0][nt]);
            oacc[1][nt] = mfma16(a1, qf, oacc[1][nt]);
        }
    }
    // epilogue: midT[s][t][h*128 + e], 4 consecutive e per lane
#pragma unroll
    for (int mt = 0; mt < 2; mt++)
#pragma unroll
        for (int nt = 0; nt < 16; nt++) {
            int t = nt * 16 + c;
            int e = wv * 32 + mt * 16 + qd * 4;
            bf16x4 o;
#pragma unroll
            for (int r = 0; r < 4; r++) o[r] = (__bf16)oacc[mt][nt][r];
            *(bf16x4*)(midT + ((size_t)s * 256 + t) * 512 + h * 128 + e) = o;
        }
}

// ---------------- final conv: y[s][o][t] = w_out[o][:] . mid[:][t] + b_out[o] ----------------
// grid (2, SG), Mtile=128, N=256, K=512. B from midT[t][f2]. y pre-offset by group.
__global__ __launch_bounds__(256) void k_out(const bf16* __restrict__ wo, const bf16* __restrict__ midT,
                                             const float* __restrict__ bo, float* __restrict__ y) {
    __shared__ bf16 lA[128 * 40];
    __shared__ bf16 lB[256 * 40];
    int o0 = blockIdx.x * 128, s = blockIdx.y;
    int tid = threadIdx.x, wv = tid >> 6, lane = tid & 63, qd = lane >> 4, c = lane & 15;
    const bf16* ms = midT + (size_t)s * 131072;  // 256*512
    f32x4 acc[2][16] = {};
    for (int k0 = 0; k0 < 512; k0 += 32) {
        __syncthreads();
        stage128(wo + (size_t)o0 * 512 + k0, 512, lA);
        stage256(ms + k0, 512, lB);
        __syncthreads();
        bf16x8 a0 = fragld(lA, wv * 32, 40), a1 = fragld(lA, wv * 32 + 16, 40);
#pragma unroll
        for (int nt = 0; nt < 16; nt++) {
            bf16x8 b = fragld(lB, nt * 16, 40);
            acc[0][nt] = mfma16(a0, b, acc[0][nt]);
            acc[1][nt] = mfma16(a1, b, acc[1][nt]);
        }
    }
    float bb[2][4];
#pragma unroll
    for (int mt = 0; mt < 2; mt++)
#pragma unroll
        for (int r = 0; r < 4; r++)
            bb[mt][r] = bo[o0 + wv * 32 + mt * 16 + qd * 4 + r];
#pragma unroll
    for (int mt = 0; mt < 2; mt++)
#pragma unroll
        for (int nt = 0; nt < 16; nt++)
#pragma unroll
            for (int r = 0; r < 4; r++) {
                int o = o0 + wv * 32 + mt * 16 + qd * 4 + r;
                int t = nt * 16 + c;
                y[((size_t)(s * 256 + o)) * 256 + t] = acc[mt][nt][r] + bb[mt][r];
            }
}

// ---------------- launch ----------------
extern "C" void kernel_launch(void* const* d_in, const int* in_sizes, int n_in,
                              void* d_out, int out_size, void* d_ws, size_t ws_size,
                              hipStream_t stream) {
    const float* x      = (const float*)d_in[0];
    const float* time_  = (const float*)d_in[1];
    const float* w_qkv  = (const float*)d_in[2];
    const float* w_time = (const float*)d_in[3];
    const float* b_time = (const float*)d_in[4];
    const float* w_out  = (const float*)d_in[5];
    const float* b_out  = (const float*)d_in[6];
    float* y = (float*)d_out;
    char* ws = (char*)d_ws;

    // Compact workspace: 72,351,744 bytes total (group-reused buffers).
    bf16*  wqkv_bf  = (bf16*)(ws + 0);            //   786432 B
    bf16*  wtime_bf = (bf16*)(ws + 786432);       //   786432 B
    bf16*  wout_bf  = (bf16*)(ws + 1572864);      //   262144 B
    bf16*  mish_bf  = (bf16*)(ws + 1835008);      //   262144 B
    float* tembT    = (float*)(ws + 2097152);     //  3145728 B  [1536][512] global
    bf16*  qt       = (bf16*)(ws + 5242880);      // 16777216 B  per group
    bf16*  kk       = (bf16*)(ws + 22020096);     // 16777216 B
    bf16*  vv       = (bf16*)(ws + 38797312);     // 16777216 B
    bf16*  midT     = (bf16*)(ws + 55574528);     // 16777216 B (ends 72351744)
    bf16*  xT       = (bf16*)(ws + 55574528);     //  8388608 B (aliases midT first half;
                                                  //  xT dead before k_attn writes midT)

    // global prep (once)
    k_cvt<<<384, 256, 0, stream>>>((const float4*)w_qkv, wqkv_bf);    // 393216 elts
    k_cvt<<<384, 256, 0, stream>>>((const float4*)w_time, wtime_bf);  // 393216
    k_cvt<<<128, 256, 0, stream>>>((const float4*)w_out, wout_bf);    // 131072
    k_mish<<<128, 256, 0, stream>>>((const float4*)time_, mish_bf);   // 131072
    k_temb<<<dim3(12, 4), 256, 0, stream>>>(wtime_bf, mish_bf, b_time, tembT);

    // per-group pipeline (stream-ordered; buffers reused each group)
    for (int g = 0; g < NGRP; g++) {
        const float* xg = x + (size_t)g * SG * FF * TT;       // 4,194,304 floats/group
        float*       yg = y + (size_t)g * SG * 256 * TT;
        const float* tg = tembT + (size_t)g * SG;             // column offset into [1536][512]
        k_xpose<<<SG * 16, 256, 0, stream>>>(xg, xT);
        k_qkv<<<dim3(12, SG), 256, 0, stream>>>(wqkv_bf, xT, tg, qt, kk, vv);
        k_attn<<<SG * 4, 256, 0, stream>>>(kk, vv, qt, midT);
        k_out<<<dim3(2, SG), 256, 0, stream>>>(wout_bf, midT, b_out, yg);
    }
}

// Round 3
// 800.493 us; speedup vs baseline: 1.2723x; 1.2723x over previous
//
#include <hip/hip_runtime.h>

// ---------------- types ----------------
typedef __bf16 bf16;
typedef __bf16 bf16x4 __attribute__((ext_vector_type(4)));
typedef __bf16 bf16x8 __attribute__((ext_vector_type(8)));
typedef float  f32x4  __attribute__((ext_vector_type(4)));

// Problem constants: b=64, a=8 -> 512 slices total, processed in 2 groups of SG=256.
// f=F=256 (DIM), t=T=256, 3*hidden=1536, heads=4, c=128
#define TT    256
#define FF    256
#define SG    256         // slices per group
#define NGRP  2

static __device__ inline f32x4 mfma16(bf16x8 a, bf16x8 b, f32x4 c) {
    return __builtin_amdgcn_mfma_f32_16x16x32_bf16(a, b, c, 0, 0, 0);
}

// ---- async global->LDS staging (16B per lane; LDS dest = wave-uniform base + lane*16) ----
typedef const __attribute__((address_space(1))) unsigned int* gp_t;
typedef __attribute__((address_space(3))) unsigned int* lp_t;
static __device__ inline void gll16(const bf16* g, bf16* l) {
    __builtin_amdgcn_global_load_lds((gp_t)g, (lp_t)l, 16, 0, 0);
}

// Stage [128][32] bf16 tile (row-major global, leading dim ld elts) -> unpadded LDS [128][32].
// 4 waves; wave w stages rows [w*32, w*32+32) via 2 instrs (16 rows per instr).
static __device__ inline void stage128g(const bf16* __restrict__ g, int ld, bf16* __restrict__ l) {
    int lane = threadIdx.x & 63, wv = threadIdx.x >> 6;
    int r = lane >> 2, c8 = (lane & 3) * 8;
#pragma unroll
    for (int i = 0; i < 2; i++) {
        int row0 = wv * 32 + i * 16;
        gll16(g + (size_t)(row0 + r) * ld + c8, l + row0 * 32);
    }
}
// Stage [256][32] bf16 tile -> unpadded LDS [256][32]. Wave w: rows [w*64, w*64+64), 4 instrs.
static __device__ inline void stage256g(const bf16* __restrict__ g, int ld, bf16* __restrict__ l) {
    int lane = threadIdx.x & 63, wv = threadIdx.x >> 6;
    int r = lane >> 2, c8 = (lane & 3) * 8;
#pragma unroll
    for (int i = 0; i < 4; i++) {
        int row0 = wv * 64 + i * 16;
        gll16(g + (size_t)(row0 + r) * ld + c8, l + row0 * 32);
    }
}
// Fragment load from unpadded [rows][32] tile: lane holds row (row0 + lane&15), k = (lane>>4)*8 + j
static __device__ inline bf16x8 fragld(const bf16* __restrict__ l, int row0) {
    int lane = threadIdx.x & 63;
    return *(const bf16x8*)(l + (row0 + (lane & 15)) * 32 + (lane >> 4) * 8);
}
// Same but explicit stride (for the ct LDS round-trip in k_attn)
static __device__ inline bf16x8 fragld_s(const bf16* __restrict__ l, int row0, int stride) {
    int lane = threadIdx.x & 63;
    return *(const bf16x8*)(l + (row0 + (lane & 15)) * stride + (lane >> 4) * 8);
}

// ---------------- small prep kernels ----------------
// fp32 -> bf16, 4 elts/thread, grid = n/1024 exactly
__global__ __launch_bounds__(256) void k_cvt(const float4* __restrict__ src, bf16* __restrict__ dst) {
    int i = blockIdx.x * 256 + threadIdx.x;
    float4 v = src[i];
    bf16x4 o;
    o[0] = (__bf16)v.x; o[1] = (__bf16)v.y; o[2] = (__bf16)v.z; o[3] = (__bf16)v.w;
    *(bf16x4*)(dst + (size_t)i * 4) = o;
}

// mish(time) fp32 -> bf16, layout [512][256]; grid 128 (4 elts/thread)
__global__ __launch_bounds__(256) void k_mish(const float4* __restrict__ src, bf16* __restrict__ dst) {
    int i = blockIdx.x * 256 + threadIdx.x;
    float4 v = src[i];
    float in[4] = {v.x, v.y, v.z, v.w};
    bf16x4 o;
#pragma unroll
    for (int j = 0; j < 4; j++) {
        float sp = log1pf(__expf(in[j]));
        o[j] = (__bf16)(in[j] * tanhf(sp));
    }
    *(bf16x4*)(dst + (size_t)i * 4) = o;
}

// x [s][f][t] fp32 -> xT [s][t][f] bf16 (64x64 LDS tiles); grid = SG*16, s is group-local
__global__ __launch_bounds__(256) void k_xpose(const float* __restrict__ x, bf16* __restrict__ xT) {
    __shared__ float tile[64][65];
    int bid = blockIdx.x;
    int s  = bid >> 4;
    int f0 = ((bid >> 2) & 3) * 64;
    int t0 = (bid & 3) * 64;
    int tid = threadIdx.x;
    int rr = tid >> 4;           // 0..15
    int cc = (tid & 15) * 4;     // 0..60
    const float* xp = x + ((size_t)(s * FF + f0)) * TT + t0;
#pragma unroll
    for (int i = 0; i < 4; i++) {
        int r = i * 16 + rr;
        float4 v = *(const float4*)(xp + (size_t)r * TT + cc);
        tile[r][cc] = v.x; tile[r][cc + 1] = v.y; tile[r][cc + 2] = v.z; tile[r][cc + 3] = v.w;
    }
    __syncthreads();
    bf16* op = xT + ((size_t)(s * TT + t0)) * FF + f0;
#pragma unroll
    for (int i = 0; i < 4; i++) {
        int tr = i * 16 + rr;
        bf16x4 o;
        o[0] = (__bf16)tile[cc][tr];     o[1] = (__bf16)tile[cc + 1][tr];
        o[2] = (__bf16)tile[cc + 2][tr]; o[3] = (__bf16)tile[cc + 3][tr];
        *(bf16x4*)(op + (size_t)tr * FF + cc) = o;
    }
}

// ---------------- temb GEMM: tembT[o][sg] = w_time[o][:] . mish[sg][:] + b_time[o] ----------------
// grid (12, 4), Mtile=128(o), Ntile=128(sg over all 512), K=256. Runs once.
__global__ __launch_bounds__(256) void k_temb(const bf16* __restrict__ wt, const bf16* __restrict__ mish,
                                              const float* __restrict__ bt, float* __restrict__ tembT) {
    __shared__ bf16 lA[128 * 32];
    __shared__ bf16 lB[128 * 32];
    int o0 = blockIdx.x * 128, s0 = blockIdx.y * 128;
    int tid = threadIdx.x, wv = tid >> 6, lane = tid & 63, qd = lane >> 4, c = lane & 15;
    f32x4 acc[2][8] = {};
    for (int k0 = 0; k0 < 256; k0 += 32) {
        __syncthreads();
        stage128g(wt + (size_t)o0 * 256 + k0, 256, lA);
        stage128g(mish + (size_t)s0 * 256 + k0, 256, lB);
        __syncthreads();
        bf16x8 a0 = fragld(lA, wv * 32), a1 = fragld(lA, wv * 32 + 16);
#pragma unroll
        for (int nt = 0; nt < 8; nt++) {
            bf16x8 b = fragld(lB, nt * 16);
            acc[0][nt] = mfma16(a0, b, acc[0][nt]);
            acc[1][nt] = mfma16(a1, b, acc[1][nt]);
        }
    }
#pragma unroll
    for (int mt = 0; mt < 2; mt++)
#pragma unroll
        for (int nt = 0; nt < 8; nt++)
#pragma unroll
            for (int r = 0; r < 4; r++) {
                int o = o0 + wv * 32 + mt * 16 + qd * 4 + r;
                int s = s0 + nt * 16 + c;
                tembT[(size_t)o * 512 + s] = acc[mt][nt][r] + bt[o];
            }
}

// ---------------- qkv GEMM: per (mc, s_local): D[128 o][256 t] = W[o][f] xT[t][f] + temb ----------------
// grid (12, SG). mc: sec = mc>>2 (0=q,1=k,2=v), h = mc&3.
// q -> qT[s][h][t][d] ; k,v -> [s][h][d][t]. tembT pre-offset by group column.
__global__ __launch_bounds__(256) void k_qkv(const bf16* __restrict__ wq, const bf16* __restrict__ xT,
                                             const float* __restrict__ tembT,
                                             bf16* __restrict__ qt, bf16* __restrict__ kk, bf16* __restrict__ vv) {
    __shared__ bf16 lA[128 * 32];
    __shared__ bf16 lB[256 * 32];
    int mc = blockIdx.x, s = blockIdx.y;
    int o0 = mc * 128;
    int tid = threadIdx.x, wv = tid >> 6, lane = tid & 63, qd = lane >> 4, c = lane & 15;
    const bf16* xs = xT + (size_t)s * (TT * FF);
    f32x4 acc[2][16] = {};
    for (int k0 = 0; k0 < 256; k0 += 32) {
        __syncthreads();
        stage128g(wq + (size_t)o0 * 256 + k0, 256, lA);
        stage256g(xs + k0, 256, lB);
        __syncthreads();
        bf16x8 a0 = fragld(lA, wv * 32), a1 = fragld(lA, wv * 32 + 16);
#pragma unroll
        for (int nt = 0; nt < 16; nt++) {
            bf16x8 b = fragld(lB, nt * 16);
            acc[0][nt] = mfma16(a0, b, acc[0][nt]);
            acc[1][nt] = mfma16(a1, b, acc[1][nt]);
        }
    }
    int sec = mc >> 2, h = mc & 3;
    float tb[2][4];
#pragma unroll
    for (int mt = 0; mt < 2; mt++)
#pragma unroll
        for (int r = 0; r < 4; r++)
            tb[mt][r] = tembT[(size_t)(o0 + wv * 32 + mt * 16 + qd * 4 + r) * 512 + s];
    if (sec == 0) {
#pragma unroll
        for (int mt = 0; mt < 2; mt++)
#pragma unroll
            for (int nt = 0; nt < 16; nt++) {
                int t = nt * 16 + c, dl = wv * 32 + mt * 16 + qd * 4;
                bf16x4 o;
#pragma unroll
                for (int r = 0; r < 4; r++) o[r] = (__bf16)(acc[mt][nt][r] + tb[mt][r]);
                *(bf16x4*)(qt + (((size_t)s * 4 + h) * 256 + t) * 128 + dl) = o;
            }
    } else {
        bf16* dst0 = (sec == 1 ? kk : vv);
#pragma unroll
        for (int mt = 0; mt < 2; mt++)
#pragma unroll
            for (int nt = 0; nt < 16; nt++) {
                int t = nt * 16 + c, dl = wv * 32 + mt * 16 + qd * 4;
                bf16* d = dst0 + (((size_t)s * 4 + h) * 128 + dl) * 256 + t;
#pragma unroll
                for (int r = 0; r < 4; r++) d[(size_t)r * 256] = (__bf16)(acc[mt][nt][r] + tb[mt][r]);
            }
    }
}

// ---------------- fused attention per (s_local, h) ----------------
// grid SG*4. softmax(k) stats + ct = v expk^T + out = ct q. Writes midT[s][t][h*128+e].
__global__ __launch_bounds__(256) void k_attn(const bf16* __restrict__ kk, const bf16* __restrict__ vv,
                                              const bf16* __restrict__ qt, bf16* __restrict__ midT) {
    __shared__ __align__(16) char smem[52224];
    float* mx = (float*)smem;                    // [128]
    float* rs = mx + 128;                        // [128]
    bf16* lA  = (bf16*)(smem + 1024);            // v tile  [128][32]  (8192 B)
    bf16* lB  = (bf16*)(smem + 1024 + 8192);     // k tile  [128][32]  (8192 B)
    bf16* lQ  = (bf16*)(smem + 1024);            // q tile  [256][32]  (16384 B, aliases lA+lB)
    bf16* lct = (bf16*)(smem + 1024 + 16384);    // ct [128][136]      (34816 B)
    int bid = blockIdx.x;
    int s = bid >> 2, h = bid & 3;
    size_t base = ((size_t)s * 4 + h) * 32768;   // 128*256
    const bf16* kb = kk + base;
    const bf16* vb = vv + base;
    int tid = threadIdx.x, wv = tid >> 6, lane = tid & 63, qd = lane >> 4, c = lane & 15;

    // phase 1: softmax stats per k-row (online max/sum), 2 threads per row
    {
        int d = tid >> 1, half = tid & 1;
        const bf16* p = kb + (size_t)d * 256 + half * 128;
        float m = -3e38f, l = 0.f;
#pragma unroll
        for (int ci = 0; ci < 16; ci++) {
            bf16x8 v8 = *(const bf16x8*)(p + ci * 8);
            float xv[8]; float cm = -3e38f;
#pragma unroll
            for (int j = 0; j < 8; j++) { xv[j] = (float)v8[j]; cm = fmaxf(cm, xv[j]); }
            if (cm > m) { l *= __expf(m - cm); m = cm; }
#pragma unroll
            for (int j = 0; j < 8; j++) l += __expf(xv[j] - m);
        }
        float mo = __shfl_xor(m, 1);
        float lo = __shfl_xor(l, 1);
        float M = fmaxf(m, mo);
        float L = l * __expf(m - M) + lo * __expf(mo - M);
        if (half == 0) { mx[d] = M; rs[d] = 1.0f / L; }
    }
    __syncthreads();

    // phase 2: ct[e][d] = sum_t v[e,t] * exp(k[d,t]-mx[d])   (A=v, B=exp(k))
    f32x4 cacc[2][8] = {};
    for (int k0 = 0; k0 < 256; k0 += 32) {
        __syncthreads();
        stage128g(vb + k0, 256, lA);
        stage128g(kb + k0, 256, lB);
        __syncthreads();
        bf16x8 a0 = fragld(lA, wv * 32), a1 = fragld(lA, wv * 32 + 16);
#pragma unroll
        for (int nt = 0; nt < 8; nt++) {
            bf16x8 kf = fragld(lB, nt * 16);
            float md = mx[nt * 16 + c];
            bf16x8 b;
#pragma unroll
            for (int j = 0; j < 8; j++) b[j] = (__bf16)__expf((float)kf[j] - md);
            cacc[0][nt] = mfma16(a0, b, cacc[0][nt]);
            cacc[1][nt] = mfma16(a1, b, cacc[1][nt]);
        }
    }
    __syncthreads();
    // phase 3a: ct -> LDS [e][d] (stride 136), scaled by 1/sum
#pragma unroll
    for (int mt = 0; mt < 2; mt++)
#pragma unroll
        for (int nt = 0; nt < 8; nt++) {
            int d = nt * 16 + c;
            float rv = rs[d];
#pragma unroll
            for (int r = 0; r < 4; r++) {
                int e = wv * 32 + mt * 16 + qd * 4 + r;
                lct[e * 136 + d] = (__bf16)(cacc[mt][nt][r] * rv);
            }
        }
    __syncthreads();
    // phase 3b: out[e][t] = sum_d ct[e][d] q[d][t]  (B from qT[t][d])
    const bf16* qb = qt + base;
    f32x4 oacc[2][16] = {};
    for (int d0 = 0; d0 < 128; d0 += 32) {
        __syncthreads();
        stage256g(qb + d0, 128, lQ);
        __syncthreads();
        bf16x8 a0 = fragld_s(lct + d0, wv * 32, 136), a1 = fragld_s(lct + d0, wv * 32 + 16, 136);
#pragma unroll
        for (int nt = 0; nt < 16; nt++) {
            bf16x8 qf = fragld(lQ, nt * 16);
            oacc[0][nt] = mfma16(a0, qf, oacc[0][nt]);
            oacc[1][nt] = mfma16(a1, qf, oacc[1][nt]);
        }
    }
    // epilogue: midT[s][t][h*128 + e]
#pragma unroll
    for (int mt = 0; mt < 2; mt++)
#pragma unroll
        for (int nt = 0; nt < 16; nt++) {
            int t = nt * 16 + c;
            int e = wv * 32 + mt * 16 + qd * 4;
            bf16x4 o;
#pragma unroll
            for (int r = 0; r < 4; r++) o[r] = (__bf16)oacc[mt][nt][r];
            *(bf16x4*)(midT + ((size_t)s * 256 + t) * 512 + h * 128 + e) = o;
        }
}

// ---------------- final conv: y[s][o][t] = w_out[o][:] . mid[:][t] + b_out[o] ----------------
// grid (2, SG), Mtile=128, N=256, K=512. B from midT[t][f2]. y pre-offset by group.
__global__ __launch_bounds__(256) void k_out(const bf16* __restrict__ wo, const bf16* __restrict__ midT,
                                             const float* __restrict__ bo, float* __restrict__ y) {
    __shared__ bf16 lA[128 * 32];
    __shared__ bf16 lB[256 * 32];
    int o0 = blockIdx.x * 128, s = blockIdx.y;
    int tid = threadIdx.x, wv = tid >> 6, lane = tid & 63, qd = lane >> 4, c = lane & 15;
    const bf16* ms = midT + (size_t)s * 131072;  // 256*512
    f32x4 acc[2][16] = {};
    for (int k0 = 0; k0 < 512; k0 += 32) {
        __syncthreads();
        stage128g(wo + (size_t)o0 * 512 + k0, 512, lA);
        stage256g(ms + k0, 512, lB);
        __syncthreads();
        bf16x8 a0 = fragld(lA, wv * 32), a1 = fragld(lA, wv * 32 + 16);
#pragma unroll
        for (int nt = 0; nt < 16; nt++) {
            bf16x8 b = fragld(lB, nt * 16);
            acc[0][nt] = mfma16(a0, b, acc[0][nt]);
            acc[1][nt] = mfma16(a1, b, acc[1][nt]);
        }
    }
    float bb[2][4];
#pragma unroll
    for (int mt = 0; mt < 2; mt++)
#pragma unroll
        for (int r = 0; r < 4; r++)
            bb[mt][r] = bo[o0 + wv * 32 + mt * 16 + qd * 4 + r];
#pragma unroll
    for (int mt = 0; mt < 2; mt++)
#pragma unroll
        for (int nt = 0; nt < 16; nt++)
#pragma unroll
            for (int r = 0; r < 4; r++) {
                int o = o0 + wv * 32 + mt * 16 + qd * 4 + r;
                int t = nt * 16 + c;
                y[((size_t)(s * 256 + o)) * 256 + t] = acc[mt][nt][r] + bb[mt][r];
            }
}

// ---------------- launch ----------------
extern "C" void kernel_launch(void* const* d_in, const int* in_sizes, int n_in,
                              void* d_out, int out_size, void* d_ws, size_t ws_size,
                              hipStream_t stream) {
    const float* x      = (const float*)d_in[0];
    const float* time_  = (const float*)d_in[1];
    const float* w_qkv  = (const float*)d_in[2];
    const float* w_time = (const float*)d_in[3];
    const float* b_time = (const float*)d_in[4];
    const float* w_out  = (const float*)d_in[5];
    const float* b_out  = (const float*)d_in[6];
    float* y = (float*)d_out;
    char* ws = (char*)d_ws;

    // Workspace (ws_size = 512 MiB measured; round-0 single-pass needed 517 MiB -> crash).
    // 2-group layout: total 273,678,336 B.
    bf16*  wqkv_bf  = (bf16*)(ws + 0);            //   786432 B
    bf16*  wtime_bf = (bf16*)(ws + 786432);       //   786432 B
    bf16*  wout_bf  = (bf16*)(ws + 1572864);      //   262144 B
    bf16*  mish_bf  = (bf16*)(ws + 1835008);      //   262144 B
    float* tembT    = (float*)(ws + 2097152);     //  3145728 B  [1536][512] global
    bf16*  qt       = (bf16*)(ws + 5242880);      // 67108864 B  per group
    bf16*  kk       = (bf16*)(ws + 72351744);     // 67108864 B
    bf16*  vv       = (bf16*)(ws + 139460608);    // 67108864 B
    bf16*  midT     = (bf16*)(ws + 206569472);    // 67108864 B (ends 273678336)
    bf16*  xT       = (bf16*)(ws + 206569472);    // 33554432 B (aliases midT first half;
                                                  //  xT dead before k_attn writes midT)

    // global prep (once)
    k_cvt<<<384, 256, 0, stream>>>((const float4*)w_qkv, wqkv_bf);    // 393216 elts
    k_cvt<<<384, 256, 0, stream>>>((const float4*)w_time, wtime_bf);  // 393216
    k_cvt<<<128, 256, 0, stream>>>((const float4*)w_out, wout_bf);    // 131072
    k_mish<<<128, 256, 0, stream>>>((const float4*)time_, mish_bf);   // 131072
    k_temb<<<dim3(12, 4), 256, 0, stream>>>(wtime_bf, mish_bf, b_time, tembT);

    // per-group pipeline
    for (int g = 0; g < NGRP; g++) {
        const float* xg = x + (size_t)g * SG * FF * TT;
        float*       yg = y + (size_t)g * SG * 256 * TT;
        const float* tg = tembT + (size_t)g * SG;             // column offset into [1536][512]
        k_xpose<<<SG * 16, 256, 0, stream>>>(xg, xT);
        k_qkv<<<dim3(12, SG), 256, 0, stream>>>(wqkv_bf, xT, tg, qt, kk, vv);
        k_attn<<<SG * 4, 256, 0, stream>>>(kk, vv, qt, midT);
        k_out<<<dim3(2, SG), 256, 0, stream>>>(wout_bf, midT, b_out, yg);
    }
}